// Round 7
// baseline (10086.539 us; speedup 1.0000x reference)
//
#include <hip/hip_runtime.h>
#include <hip/hip_bf16.h>

typedef unsigned short u16;
typedef unsigned int   u32;
typedef unsigned long long u64;
typedef __attribute__((ext_vector_type(8))) __bf16 bf16x8;
typedef __attribute__((ext_vector_type(4))) float   f32x4;

// async global->LDS, 16B per lane; LDS dest = wave-uniform base + lane*16
#define GLOAD16(gp, lp) __builtin_amdgcn_global_load_lds( \
    (__attribute__((address_space(1))) void*)(gp),        \
    (__attribute__((address_space(3))) void*)(lp), 16, 0, 0)

static __device__ __forceinline__ u16 f2bf(float f) {
  __bf16 b = (__bf16)f;                 // RNE convert
  return __builtin_bit_cast(u16, b);
}
static __device__ __forceinline__ f32x4 mfma16(bf16x8 a, bf16x8 b, f32x4 c) {
  return __builtin_amdgcn_mfma_f32_16x16x32_bf16(a, b, c, 0, 0, 0);
}

// ---------------- prep kernels ----------------

__global__ __launch_bounds__(256) void k_cvt_emb(const float* __restrict__ s,
                                                 u16* __restrict__ d) {
  int i = (blockIdx.x * 256 + threadIdx.x) * 4;
  float4 v = *(const float4*)(s + i);
  d[i] = f2bf(v.x); d[i+1] = f2bf(v.y); d[i+2] = f2bf(v.z); d[i+3] = f2bf(v.w);
}

__global__ __launch_bounds__(256) void k_tr_wh(const float* __restrict__ Wh,
                                               u16* __restrict__ WhxT,
                                               u16* __restrict__ WhhT) {
  __shared__ float tile[32][33];
  int bx = blockIdx.x & 31;
  int be = blockIdx.x >> 5;
  int tx = threadIdx.x & 31, ty = threadIdx.x >> 5;
  #pragma unroll
  for (int s = 0; s < 32; s += 8)
    tile[ty + s][tx] = Wh[(size_t)(be*32 + ty + s) * 1024 + bx*32 + tx];
  __syncthreads();
  #pragma unroll
  for (int s = 0; s < 32; s += 8) {
    int e = be*32 + tx;
    int j = bx*32 + ty + s;
    u16 v = f2bf(tile[tx][ty + s]);
    if (e < 512) WhxT[(size_t)j * 512 + e] = v;
    else         WhhT[(size_t)j * 1024 + (e - 512)] = v;
  }
}

__global__ __launch_bounds__(256) void k_tr_wo(const float* __restrict__ Wo,
                                               u16* __restrict__ WoT) {
  __shared__ float tile[32][33];
  int bx = blockIdx.x & 255;
  int by = blockIdx.x >> 8;
  int tx = threadIdx.x & 31, ty = threadIdx.x >> 5;
  #pragma unroll
  for (int s = 0; s < 32; s += 8)
    tile[ty + s][tx] = Wo[(size_t)(by*32 + ty + s) * 8192 + bx*32 + tx];
  __syncthreads();
  #pragma unroll
  for (int s = 0; s < 32; s += 8)
    WoT[(size_t)(bx*32 + ty + s) * 1024 + by*32 + tx] = f2bf(tile[tx][ty + s]);
}

// h0 -> ring slot 0; zero flags
__global__ __launch_bounds__(256) void k_init(const float* __restrict__ hid,
                                              u16* __restrict__ ring,
                                              unsigned* __restrict__ flags) {
  int i = blockIdx.x * 256 + threadIdx.x;
  ring[i] = f2bf(hid[i]);
  if (blockIdx.x < 8) flags[i] = 0;      // zero the full padded 8 KB flag region
}

// ---------------- phase 1: xpart = gather(emb) @ WhxT^T + b_h ----------------
__global__ __launch_bounds__(256) void k_xpart(const int* __restrict__ xq,
                                               const u16* __restrict__ embB,
                                               const u16* __restrict__ WhxT,
                                               const float* __restrict__ bh,
                                               float* __restrict__ xpart) {
  __shared__ __align__(16) u16 As[128 * 32];
  __shared__ __align__(16) u16 Bs[128 * 32];
  __shared__ int sx[128];
  int bid = blockIdx.x;
  int cpx = gridDim.x >> 3;
  int swz = (bid & 7) * cpx + (bid >> 3);
  int tm = (swz >> 3) * 128, tn = (swz & 7) * 128;
  int tid = threadIdx.x, lane = tid & 63, w = tid >> 6;
  int wm = (w >> 1) * 64, wn = (w & 1) * 64;
  if (tid < 128) sx[tid] = xq[tm + tid];
  __syncthreads();
  int r0 = tid >> 2, sub = tid & 3;
  const u16* ga0 = embB + (size_t)sx[r0] * 512 + sub * 8;
  const u16* ga1 = embB + (size_t)sx[64 + r0] * 512 + sub * 8;
  const u16* gb0 = WhxT + (size_t)(tn + r0) * 512 + sub * 8;
  const u16* gb1 = WhxT + (size_t)(tn + 64 + r0) * 512 + sub * 8;
  f32x4 acc[4][4] = {};
  int rl = lane & 15, kb = (lane >> 4) * 8;
  for (int kt = 0; kt < 16; ++kt) {
    int k0 = kt * 32;
    __syncthreads();
    GLOAD16(ga0 + k0, As + w * 512);
    GLOAD16(ga1 + k0, As + 2048 + w * 512);
    GLOAD16(gb0 + k0, Bs + w * 512);
    GLOAD16(gb1 + k0, Bs + 2048 + w * 512);
    __syncthreads();
    bf16x8 af[4], bf[4];
    #pragma unroll
    for (int mi = 0; mi < 4; mi++) af[mi] = *(const bf16x8*)&As[(wm + mi*16 + rl) * 32 + kb];
    #pragma unroll
    for (int ni = 0; ni < 4; ni++) bf[ni] = *(const bf16x8*)&Bs[(wn + ni*16 + rl) * 32 + kb];
    #pragma unroll
    for (int mi = 0; mi < 4; mi++)
      #pragma unroll
      for (int ni = 0; ni < 4; ni++)
        acc[mi][ni] = mfma16(af[mi], bf[ni], acc[mi][ni]);
  }
  int rq = (lane >> 4) << 2;
  #pragma unroll
  for (int ni = 0; ni < 4; ni++) {
    int col = tn + wn + ni*16 + rl;
    float bias = bh[col];
    #pragma unroll
    for (int mi = 0; mi < 4; mi++) {
      int row = tm + wm + mi*16 + rq;
      #pragma unroll
      for (int r = 0; r < 4; r++)
        xpart[(size_t)(row + r) * 1024 + col] = acc[mi][ni][r] + bias;
    }
  }
}

// ---------------- phase 2: persistent recurrence ----------------
// 16 blocks x 512 threads (8 waves); block owns 64 j-columns; zero LDS.
// Wave (jt,bt): C tile j16 x b16, FULL K=1024 in-wave (no cross-wave reduce).
// A-operand = Whh rows (j, in 128 VGPRs, loop-invariant); B-operand = h rows
// (b, reloaded per step in two 64-VGPR half-chunks). C layout: lane owns
// 4 consecutive j (rows kq*4+r) for one batch (col rl) -> 8B h-store,
// float4 xpart prefetch, float4 hfinal.
// Sync (proven in r5): agent-scope relaxed atomics for h + flags; release =
// per-thread vmcnt(0) drain + barrier before tid0's flag store; wave-0 polls
// 16 padded flags (128B apart).
__global__ __launch_bounds__(512, 2) void k_rnn(const u16* __restrict__ WhhT,
                                                const float* __restrict__ xpart,
                                                u16* __restrict__ ring,
                                                float* __restrict__ hfinal,
                                                unsigned* __restrict__ flags) {
  const int bid = blockIdx.x, tid = threadIdx.x;
  const int lane = tid & 63, wv = tid >> 6;       // 8 waves
  const int jt = wv >> 1, bt = wv & 1;            // 4 j-tiles x 2 b-tiles
  const int rl = lane & 15, kq = lane >> 4;       // kq in [0,4)
  const int kb = kq * 8;
  const int jbase = bid * 64;
  const int jA = jbase + jt * 16 + rl;            // W row this lane loads (A frag)
  const int bB = bt * 16 + rl;                    // h row this lane loads (B frag)
                                                  //  == this lane's OUTPUT batch (C col)
  const int j0 = jbase + jt * 16 + kq * 4;        // first of 4 output j (C rows)

  // W fragments resident in VGPRs for the whole kernel (128 VGPRs)
  bf16x8 Wreg[32];
  { const u16* wp = WhhT + (size_t)jA * 1024 + kb;
    #pragma unroll
    for (int kt = 0; kt < 32; ++kt) Wreg[kt] = *(const bf16x8*)(wp + kt * 32); }

  // xpart prefetch for t=0 (xpart row = b*1024 + t)
  float4 xpre = *(const float4*)&xpart[(size_t)bB * 1048576 + j0];

  for (int t = 0; t < 1024; ++t) {
    const u16* hp = ring + (size_t)t * 32768 + (size_t)bB * 1024 + kb;
    f32x4 a0 = {0.f,0.f,0.f,0.f}, a1 = {0.f,0.f,0.f,0.f};
    // two half-K chunks keep live h regs at 64 VGPRs
    {
      bf16x8 ha[16];
      #pragma unroll
      for (int kt = 0; kt < 16; ++kt) ha[kt] = *(const bf16x8*)(hp + kt * 32);
      #pragma unroll
      for (int kt = 0; kt < 16; kt += 2) {
        a0 = mfma16(Wreg[kt],     ha[kt],     a0);
        a1 = mfma16(Wreg[kt + 1], ha[kt + 1], a1);
      }
    }
    {
      bf16x8 ha[16];
      #pragma unroll
      for (int kt = 0; kt < 16; ++kt) ha[kt] = *(const bf16x8*)(hp + 512 + kt * 32);
      #pragma unroll
      for (int kt = 0; kt < 16; kt += 2) {
        a0 = mfma16(Wreg[16 + kt], ha[kt],     a0);
        a1 = mfma16(Wreg[17 + kt], ha[kt + 1], a1);
      }
    }
    f32x4 s = a0 + a1;
    float v0 = tanhf(s[0] + xpre.x);
    float v1 = tanhf(s[1] + xpre.y);
    float v2 = tanhf(s[2] + xpre.z);
    float v3 = tanhf(s[3] + xpre.w);
    u32 lo = (u32)f2bf(v0) | ((u32)f2bf(v1) << 16);
    u32 hi = (u32)f2bf(v2) | ((u32)f2bf(v3) << 16);
    u64 hv = (u64)lo | ((u64)hi << 32);
    // h store: 4 consecutive j for batch bB -> ring slot t+1 (agent scope)
    __hip_atomic_store((u64*)(ring + (size_t)(t + 1) * 32768 + (size_t)bB * 1024 + j0),
                       hv, __ATOMIC_RELAXED, __HIP_MEMORY_SCOPE_AGENT);
    if (t == 1023) {
      *(float4*)&hfinal[(size_t)bB * 1024 + j0] = make_float4(v0, v1, v2, v3);
    } else {
      // release: drain own stores to the coherence point, order via barrier,
      // then tid0 posts the flag. No cache-maintenance instructions.
      asm volatile("s_waitcnt vmcnt(0)" ::: "memory");
      __syncthreads();
      if (tid == 0)
        __hip_atomic_store(&flags[bid * 32], (unsigned)(t + 1),
                           __ATOMIC_RELAXED, __HIP_MEMORY_SCOPE_AGENT);
      // prefetch next xpart under the poll
      xpre = *(const float4*)&xpart[(size_t)bB * 1048576 + (size_t)(t + 1) * 1024 + j0];
      if (wv == 0) {                     // 4 lanes watch each of the 16 flags
        unsigned tgt = (unsigned)(t + 1);
        for (;;) {
          unsigned v = __hip_atomic_load(&flags[(lane & 15) * 32], __ATOMIC_RELAXED,
                                         __HIP_MEMORY_SCOPE_AGENT);
          if (!__any((int)(v < tgt))) break;
        }
      }
      __syncthreads();
    }
  }
}

// ---------------- phase 3: logits = ringA @ WoT^T + b_o ----------------
// A row m corresponds to (t = m>>5, b = m&31); output row = b*1024 + t.
__global__ __launch_bounds__(256) void k_logits(const u16* __restrict__ A,
                                                const u16* __restrict__ BT,
                                                const float* __restrict__ bo,
                                                float* __restrict__ C) {
  __shared__ __align__(16) u16 As[128 * 32];
  __shared__ __align__(16) u16 Bs[128 * 32];
  int bid = blockIdx.x;
  int cpx = gridDim.x >> 3;
  int swz = (bid & 7) * cpx + (bid >> 3);
  int tm = (swz >> 6) * 128, tn = (swz & 63) * 128;
  int tid = threadIdx.x, lane = tid & 63, w = tid >> 6;
  int wm = (w >> 1) * 64, wn = (w & 1) * 64;
  int r0 = tid >> 2, sub = tid & 3;
  const u16* ga0 = A + (size_t)(tm + r0) * 1024 + sub * 8;
  const u16* ga1 = A + (size_t)(tm + 64 + r0) * 1024 + sub * 8;
  const u16* gb0 = BT + (size_t)(tn + r0) * 1024 + sub * 8;
  const u16* gb1 = BT + (size_t)(tn + 64 + r0) * 1024 + sub * 8;
  f32x4 acc[4][4] = {};
  int rl = lane & 15, kb = (lane >> 4) * 8;
  for (int kt = 0; kt < 32; ++kt) {
    int k0 = kt * 32;
    __syncthreads();
    GLOAD16(ga0 + k0, As + w * 512);
    GLOAD16(ga1 + k0, As + 2048 + w * 512);
    GLOAD16(gb0 + k0, Bs + w * 512);
    GLOAD16(gb1 + k0, Bs + 2048 + w * 512);
    __syncthreads();
    bf16x8 af[4], bf[4];
    #pragma unroll
    for (int mi = 0; mi < 4; mi++) af[mi] = *(const bf16x8*)&As[(wm + mi*16 + rl) * 32 + kb];
    #pragma unroll
    for (int ni = 0; ni < 4; ni++) bf[ni] = *(const bf16x8*)&Bs[(wn + ni*16 + rl) * 32 + kb];
    #pragma unroll
    for (int mi = 0; mi < 4; mi++)
      #pragma unroll
      for (int ni = 0; ni < 4; ni++)
        acc[mi][ni] = mfma16(af[mi], bf[ni], acc[mi][ni]);
  }
  int rq = (lane >> 4) << 2;
  #pragma unroll
  for (int ni = 0; ni < 4; ni++) {
    int col = tn + wn + ni*16 + rl;
    float bias = bo[col];
    #pragma unroll
    for (int mi = 0; mi < 4; mi++) {
      int row = tm + wm + mi*16 + rq;
      #pragma unroll
      for (int r = 0; r < 4; r++) {
        int m = row + r;
        size_t orow = (size_t)(((m & 31) << 10) | (m >> 5));
        C[orow * 8192 + col] = acc[mi][ni][r] + bias;
      }
    }
  }
}

// ---------------- launch ----------------
extern "C" void kernel_launch(void* const* d_in, const int* in_sizes, int n_in,
                              void* d_out, int out_size, void* d_ws, size_t ws_size,
                              hipStream_t stream) {
  const int*   x   = (const int*)  d_in[0];
  const float* hid = (const float*)d_in[1];
  const float* emb = (const float*)d_in[2];
  const float* Wh  = (const float*)d_in[3];
  const float* bh  = (const float*)d_in[4];
  const float* Wo  = (const float*)d_in[5];
  const float* bo  = (const float*)d_in[6];
  float* logits = (float*)d_out;                       // [32768][8192]
  float* hfinal = logits + (size_t)32768 * 8192;       // [32][1024]

  char* ws = (char*)d_ws;
  size_t off = 0;
  auto alloc = [&](size_t bytes) {
    char* p = ws + off;
    off += (bytes + 255) & ~(size_t)255;
    return p;
  };
  u16*   embB  = (u16*)  alloc((size_t)8192 * 512 * 2);    //  8 MB
  u16*   WhxT  = (u16*)  alloc((size_t)1024 * 512 * 2);    //  1 MB
  u16*   WhhT  = (u16*)  alloc((size_t)1024 * 1024 * 2);   //  2 MB
  u16*   WoT   = (u16*)  alloc((size_t)8192 * 1024 * 2);   // 16 MB
  float* xpart = (float*)alloc((size_t)32768 * 1024 * 4);  // 128 MB, row=b*1024+t
  u16*   ring  = (u16*)  alloc((size_t)1025 * 32768 * 2);  // 67.1 MB (slot t = h_t)
  unsigned* flags = (unsigned*)alloc(8192);                // 16 flags, 128B apart
  (void)ws_size; (void)in_sizes; (void)n_in; (void)out_size;

  k_cvt_emb<<<4096, 256, 0, stream>>>(emb, embB);
  k_tr_wh  <<<1536, 256, 0, stream>>>(Wh, WhxT, WhhT);
  k_tr_wo  <<<8192, 256, 0, stream>>>(Wo, WoT);
  k_init   <<<128,  256, 0, stream>>>(hid, ring, flags);
  k_xpart  <<<2048, 256, 0, stream>>>(x, embB, WhxT, bh, xpart);
  k_rnn    <<<16,   512, 0, stream>>>(WhhT, xpart, ring, hfinal, flags);
  k_logits <<<16384,256, 0, stream>>>(ring + 32768, WoT, bo, logits);
}

// Round 8
// 6432.286 us; speedup vs baseline: 1.5681x; 1.5681x over previous
//
#include <hip/hip_runtime.h>
#include <hip/hip_bf16.h>

typedef unsigned short u16;
typedef unsigned int   u32;
typedef unsigned long long u64;
typedef __attribute__((ext_vector_type(8))) __bf16 bf16x8;
typedef __attribute__((ext_vector_type(4))) float   f32x4;

// async global->LDS, 16B per lane; LDS dest = wave-uniform base + lane*16
#define GLOAD16(gp, lp) __builtin_amdgcn_global_load_lds( \
    (__attribute__((address_space(1))) void*)(gp),        \
    (__attribute__((address_space(3))) void*)(lp), 16, 0, 0)

static __device__ __forceinline__ u16 f2bf(float f) {
  __bf16 b = (__bf16)f;                 // RNE convert
  return __builtin_bit_cast(u16, b);
}
static __device__ __forceinline__ f32x4 mfma16(bf16x8 a, bf16x8 b, f32x4 c) {
  return __builtin_amdgcn_mfma_f32_16x16x32_bf16(a, b, c, 0, 0, 0);
}

// ---------------- prep kernels ----------------

__global__ __launch_bounds__(256) void k_cvt_emb(const float* __restrict__ s,
                                                 u16* __restrict__ d) {
  int i = (blockIdx.x * 256 + threadIdx.x) * 4;
  float4 v = *(const float4*)(s + i);
  d[i] = f2bf(v.x); d[i+1] = f2bf(v.y); d[i+2] = f2bf(v.z); d[i+3] = f2bf(v.w);
}

__global__ __launch_bounds__(256) void k_tr_wh(const float* __restrict__ Wh,
                                               u16* __restrict__ WhxT,
                                               u16* __restrict__ WhhT) {
  __shared__ float tile[32][33];
  int bx = blockIdx.x & 31;
  int be = blockIdx.x >> 5;
  int tx = threadIdx.x & 31, ty = threadIdx.x >> 5;
  #pragma unroll
  for (int s = 0; s < 32; s += 8)
    tile[ty + s][tx] = Wh[(size_t)(be*32 + ty + s) * 1024 + bx*32 + tx];
  __syncthreads();
  #pragma unroll
  for (int s = 0; s < 32; s += 8) {
    int e = be*32 + tx;
    int j = bx*32 + ty + s;
    u16 v = f2bf(tile[tx][ty + s]);
    if (e < 512) WhxT[(size_t)j * 512 + e] = v;
    else         WhhT[(size_t)j * 1024 + (e - 512)] = v;
  }
}

__global__ __launch_bounds__(256) void k_tr_wo(const float* __restrict__ Wo,
                                               u16* __restrict__ WoT) {
  __shared__ float tile[32][33];
  int bx = blockIdx.x & 255;
  int by = blockIdx.x >> 8;
  int tx = threadIdx.x & 31, ty = threadIdx.x >> 5;
  #pragma unroll
  for (int s = 0; s < 32; s += 8)
    tile[ty + s][tx] = Wo[(size_t)(by*32 + ty + s) * 8192 + bx*32 + tx];
  __syncthreads();
  #pragma unroll
  for (int s = 0; s < 32; s += 8)
    WoT[(size_t)(bx*32 + ty + s) * 1024 + by*32 + tx] = f2bf(tile[tx][ty + s]);
}

// h0 -> ring slot 0; zero 16KB flag region (8 jobs x 16 flags, 128B apart)
__global__ __launch_bounds__(256) void k_init(const float* __restrict__ hid,
                                              u16* __restrict__ ring,
                                              unsigned* __restrict__ flags) {
  int i = blockIdx.x * 256 + threadIdx.x;
  ring[i] = f2bf(hid[i]);
  if (blockIdx.x < 16) flags[i] = 0;
}

// ---------------- phase 1: xpart = gather(emb) @ WhxT^T + b_h ----------------
__global__ __launch_bounds__(256) void k_xpart(const int* __restrict__ xq,
                                               const u16* __restrict__ embB,
                                               const u16* __restrict__ WhxT,
                                               const float* __restrict__ bh,
                                               float* __restrict__ xpart) {
  __shared__ __align__(16) u16 As[128 * 32];
  __shared__ __align__(16) u16 Bs[128 * 32];
  __shared__ int sx[128];
  int bid = blockIdx.x;
  int cpx = gridDim.x >> 3;
  int swz = (bid & 7) * cpx + (bid >> 3);
  int tm = (swz >> 3) * 128, tn = (swz & 7) * 128;
  int tid = threadIdx.x, lane = tid & 63, w = tid >> 6;
  int wm = (w >> 1) * 64, wn = (w & 1) * 64;
  if (tid < 128) sx[tid] = xq[tm + tid];
  __syncthreads();
  int r0 = tid >> 2, sub = tid & 3;
  const u16* ga0 = embB + (size_t)sx[r0] * 512 + sub * 8;
  const u16* ga1 = embB + (size_t)sx[64 + r0] * 512 + sub * 8;
  const u16* gb0 = WhxT + (size_t)(tn + r0) * 512 + sub * 8;
  const u16* gb1 = WhxT + (size_t)(tn + 64 + r0) * 512 + sub * 8;
  f32x4 acc[4][4] = {};
  int rl = lane & 15, kb = (lane >> 4) * 8;
  for (int kt = 0; kt < 16; ++kt) {
    int k0 = kt * 32;
    __syncthreads();
    GLOAD16(ga0 + k0, As + w * 512);
    GLOAD16(ga1 + k0, As + 2048 + w * 512);
    GLOAD16(gb0 + k0, Bs + w * 512);
    GLOAD16(gb1 + k0, Bs + 2048 + w * 512);
    __syncthreads();
    bf16x8 af[4], bf[4];
    #pragma unroll
    for (int mi = 0; mi < 4; mi++) af[mi] = *(const bf16x8*)&As[(wm + mi*16 + rl) * 32 + kb];
    #pragma unroll
    for (int ni = 0; ni < 4; ni++) bf[ni] = *(const bf16x8*)&Bs[(wn + ni*16 + rl) * 32 + kb];
    #pragma unroll
    for (int mi = 0; mi < 4; mi++)
      #pragma unroll
      for (int ni = 0; ni < 4; ni++)
        acc[mi][ni] = mfma16(af[mi], bf[ni], acc[mi][ni]);
  }
  int rq = (lane >> 4) << 2;
  #pragma unroll
  for (int ni = 0; ni < 4; ni++) {
    int col = tn + wn + ni*16 + rl;
    float bias = bh[col];
    #pragma unroll
    for (int mi = 0; mi < 4; mi++) {
      int row = tm + wm + mi*16 + rq;
      #pragma unroll
      for (int r = 0; r < 4; r++)
        xpart[(size_t)(row + r) * 1024 + col] = acc[mi][ni][r] + bias;
    }
  }
}

// ---------------- phase 2: per-batch-split persistent recurrence ----------------
// The recurrence is per-batch independent. 8 jobs x 4 batches; each job run by
// 16 blocks x 256 thr (1 block/CU, LDS-bound). Block owns 64 j-cols; its W
// slice (64x1024 bf16 = 128KB) lives in LDS, XOR-swizzled (k ^= (j&7)<<3) so
// A-frag ds_read_b128 spreads uniformly over banks. Each wave computes a full
// K=1024 j-tile (no cross-wave reduce, no psh). B-operand = h rows of the 4
// job batches (cols 0..3 of the MFMA; cols 4..15 duplicate — unused), loaded
// with plain cached loads (first touch post-gate => fresh => safe; r5-proven).
// Sync per job (r5 protocol): 8B sc1-atomic h-stores -> vmcnt(0) drain ->
// barrier -> tid0 posts flag -> wave0 polls the job's 16 padded flags.
__global__ __launch_bounds__(256) void k_rnn(const u16* __restrict__ WhhT,
                                             const float* __restrict__ xpart,
                                             u16* __restrict__ ring,
                                             float* __restrict__ hfinal,
                                             unsigned* __restrict__ flags) {
  __shared__ __align__(16) u16 Wlds[64 * 1024];       // 128KB, swizzled
  const int bid = blockIdx.x, tid = threadIdx.x;
  const int lane = tid & 63, wv = tid >> 6;           // 4 waves = 4 j-tiles
  const int jb = bid >> 4;                            // job 0..7
  const int n  = bid & 15;                            // slot in job
  const int jbase = n * 64;
  const int b0 = jb * 4;                              // first of 4 batches
  const int rl = lane & 15, kq = lane >> 4;           // frag coords
  const int cc = lane & 3;                            // batch sub-index (dup x4)
  const int rq = kq << 2;
  const int j0 = jbase + wv * 16 + rq;                // first of 4 output j
  const int c  = lane & 15;                           // C col (batch if <4)

  // stage W slice -> LDS (once): element (j,k) -> Wlds[j*1024 + (k ^ ((j&7)<<3))]
  for (int e = tid * 8; e < 65536; e += 2048) {
    int j = e >> 10;
    bf16x8 wval = *(const bf16x8*)&WhhT[(size_t)(jbase + j) * 1024 + (e & 1023)];
    *(bf16x8*)&Wlds[e ^ ((j & 7) << 3)] = wval;
  }
  __syncthreads();

  const int arow = (wv * 16 + rl) * 1024 + kq * 8;    // A element base (pre-XOR)
  const int xr = (rl & 7) << 3;

  unsigned* fpost = flags + (jb * 16 + n) * 32;
  const unsigned* fpoll = flags + (jb * 16 + (lane & 15)) * 32;

  // xpart prefetch for t=0 (xpart row = b*1024 + t)
  float4 xpre = *(const float4*)&xpart[(size_t)(b0 + cc) * 1048576 + j0];

  for (int t = 0; t < 1024; ++t) {
    const u16* hb = ring + (size_t)t * 32768 + (size_t)(b0 + cc) * 1024 + kq * 8;
    f32x4 a0 = {0.f,0.f,0.f,0.f}, a1 = a0, a2 = a0, a3 = a0;
    #pragma unroll
    for (int ch = 0; ch < 32; ch += 4) {
      bf16x8 w0 = *(const bf16x8*)&Wlds[(arow + (ch+0)*32) ^ xr];
      bf16x8 w1 = *(const bf16x8*)&Wlds[(arow + (ch+1)*32) ^ xr];
      bf16x8 w2 = *(const bf16x8*)&Wlds[(arow + (ch+2)*32) ^ xr];
      bf16x8 w3 = *(const bf16x8*)&Wlds[(arow + (ch+3)*32) ^ xr];
      bf16x8 h0 = *(const bf16x8*)(hb + (ch+0)*32);
      bf16x8 h1 = *(const bf16x8*)(hb + (ch+1)*32);
      bf16x8 h2 = *(const bf16x8*)(hb + (ch+2)*32);
      bf16x8 h3 = *(const bf16x8*)(hb + (ch+3)*32);
      a0 = mfma16(w0, h0, a0);
      a1 = mfma16(w1, h1, a1);
      a2 = mfma16(w2, h2, a2);
      a3 = mfma16(w3, h3, a3);
    }
    f32x4 s = (a0 + a1) + (a2 + a3);
    float v0 = tanhf(s[0] + xpre.x);
    float v1 = tanhf(s[1] + xpre.y);
    float v2 = tanhf(s[2] + xpre.z);
    float v3 = tanhf(s[3] + xpre.w);
    if (c < 4) {                                      // real batch cols only
      u32 lo = (u32)f2bf(v0) | ((u32)f2bf(v1) << 16);
      u32 hi = (u32)f2bf(v2) | ((u32)f2bf(v3) << 16);
      u64 hv = (u64)lo | ((u64)hi << 32);
      __hip_atomic_store((u64*)(ring + (size_t)(t + 1) * 32768 + (size_t)(b0 + c) * 1024 + j0),
                         hv, __ATOMIC_RELAXED, __HIP_MEMORY_SCOPE_AGENT);
      if (t == 1023)
        *(float4*)&hfinal[(size_t)(b0 + c) * 1024 + j0] = make_float4(v0, v1, v2, v3);
    }
    if (t < 1023) {
      // release: drain own stores to the coherence point, order via barrier,
      // then tid0 posts the job-local flag. No cache-maintenance instructions.
      asm volatile("s_waitcnt vmcnt(0)" ::: "memory");
      __syncthreads();
      if (tid == 0)
        __hip_atomic_store(fpost, (unsigned)(t + 1),
                           __ATOMIC_RELAXED, __HIP_MEMORY_SCOPE_AGENT);
      // prefetch next xpart under the poll
      xpre = *(const float4*)&xpart[(size_t)(b0 + cc) * 1048576 + (size_t)(t + 1) * 1024 + j0];
      if (wv == 0) {                                  // poll this job's 16 flags
        unsigned tgt = (unsigned)(t + 1);
        for (;;) {
          unsigned v = __hip_atomic_load(fpoll, __ATOMIC_RELAXED,
                                         __HIP_MEMORY_SCOPE_AGENT);
          if (!__any((int)(v < tgt))) break;
        }
      }
      __syncthreads();
    }
  }
}

// ---------------- phase 3: logits = ringA @ WoT^T + b_o ----------------
// A row m corresponds to (t = m>>5, b = m&31); output row = b*1024 + t.
__global__ __launch_bounds__(256) void k_logits(const u16* __restrict__ A,
                                                const u16* __restrict__ BT,
                                                const float* __restrict__ bo,
                                                float* __restrict__ C) {
  __shared__ __align__(16) u16 As[128 * 32];
  __shared__ __align__(16) u16 Bs[128 * 32];
  int bid = blockIdx.x;
  int cpx = gridDim.x >> 3;
  int swz = (bid & 7) * cpx + (bid >> 3);
  int tm = (swz >> 6) * 128, tn = (swz & 63) * 128;
  int tid = threadIdx.x, lane = tid & 63, w = tid >> 6;
  int wm = (w >> 1) * 64, wn = (w & 1) * 64;
  int r0 = tid >> 2, sub = tid & 3;
  const u16* ga0 = A + (size_t)(tm + r0) * 1024 + sub * 8;
  const u16* ga1 = A + (size_t)(tm + 64 + r0) * 1024 + sub * 8;
  const u16* gb0 = BT + (size_t)(tn + r0) * 1024 + sub * 8;
  const u16* gb1 = BT + (size_t)(tn + 64 + r0) * 1024 + sub * 8;
  f32x4 acc[4][4] = {};
  int rl = lane & 15, kb = (lane >> 4) * 8;
  for (int kt = 0; kt < 32; ++kt) {
    int k0 = kt * 32;
    __syncthreads();
    GLOAD16(ga0 + k0, As + w * 512);
    GLOAD16(ga1 + k0, As + 2048 + w * 512);
    GLOAD16(gb0 + k0, Bs + w * 512);
    GLOAD16(gb1 + k0, Bs + 2048 + w * 512);
    __syncthreads();
    bf16x8 af[4], bf[4];
    #pragma unroll
    for (int mi = 0; mi < 4; mi++) af[mi] = *(const bf16x8*)&As[(wm + mi*16 + rl) * 32 + kb];
    #pragma unroll
    for (int ni = 0; ni < 4; ni++) bf[ni] = *(const bf16x8*)&Bs[(wn + ni*16 + rl) * 32 + kb];
    #pragma unroll
    for (int mi = 0; mi < 4; mi++)
      #pragma unroll
      for (int ni = 0; ni < 4; ni++)
        acc[mi][ni] = mfma16(af[mi], bf[ni], acc[mi][ni]);
  }
  int rq = (lane >> 4) << 2;
  #pragma unroll
  for (int ni = 0; ni < 4; ni++) {
    int col = tn + wn + ni*16 + rl;
    float bias = bo[col];
    #pragma unroll
    for (int mi = 0; mi < 4; mi++) {
      int row = tm + wm + mi*16 + rq;
      #pragma unroll
      for (int r = 0; r < 4; r++) {
        int m = row + r;
        size_t orow = (size_t)(((m & 31) << 10) | (m >> 5));
        C[orow * 8192 + col] = acc[mi][ni][r] + bias;
      }
    }
  }
}

// ---------------- launch ----------------
extern "C" void kernel_launch(void* const* d_in, const int* in_sizes, int n_in,
                              void* d_out, int out_size, void* d_ws, size_t ws_size,
                              hipStream_t stream) {
  const int*   x   = (const int*)  d_in[0];
  const float* hid = (const float*)d_in[1];
  const float* emb = (const float*)d_in[2];
  const float* Wh  = (const float*)d_in[3];
  const float* bh  = (const float*)d_in[4];
  const float* Wo  = (const float*)d_in[5];
  const float* bo  = (const float*)d_in[6];
  float* logits = (float*)d_out;                       // [32768][8192]
  float* hfinal = logits + (size_t)32768 * 8192;       // [32][1024]

  char* ws = (char*)d_ws;
  size_t off = 0;
  auto alloc = [&](size_t bytes) {
    char* p = ws + off;
    off += (bytes + 255) & ~(size_t)255;
    return p;
  };
  u16*   embB  = (u16*)  alloc((size_t)8192 * 512 * 2);    //  8 MB
  u16*   WhxT  = (u16*)  alloc((size_t)1024 * 512 * 2);    //  1 MB
  u16*   WhhT  = (u16*)  alloc((size_t)1024 * 1024 * 2);   //  2 MB
  u16*   WoT   = (u16*)  alloc((size_t)8192 * 1024 * 2);   // 16 MB
  float* xpart = (float*)alloc((size_t)32768 * 1024 * 4);  // 128 MB, row=b*1024+t
  u16*   ring  = (u16*)  alloc((size_t)1025 * 32768 * 2);  // 67.1 MB (slot t = h_t)
  unsigned* flags = (unsigned*)alloc(16384);               // 128 flags, 128B apart
  (void)ws_size; (void)in_sizes; (void)n_in; (void)out_size;

  k_cvt_emb<<<4096, 256, 0, stream>>>(emb, embB);
  k_tr_wh  <<<1536, 256, 0, stream>>>(Wh, WhxT, WhhT);
  k_tr_wo  <<<8192, 256, 0, stream>>>(Wo, WoT);
  k_init   <<<128,  256, 0, stream>>>(hid, ring, flags);
  k_xpart  <<<2048, 256, 0, stream>>>(x, embB, WhxT, bh, xpart);
  k_rnn    <<<128,  256, 0, stream>>>(WhhT, xpart, ring, hfinal, flags);
  k_logits <<<16384,256, 0, stream>>>(ring + 32768, WoT, bo, logits);
}